// Round 12
// baseline (342.669 us; speedup 1.0000x reference)
//
#include <hip/hip_runtime.h>
#include <hip/hip_bf16.h>

typedef unsigned short u16;
typedef unsigned int u32;
typedef __attribute__((ext_vector_type(8))) short short8;   // 8 bf16 for MFMA frags
typedef __attribute__((ext_vector_type(8))) u16 ushort8;
typedef __attribute__((ext_vector_type(4))) float f32x4;

// ---------- constants ----------
#define BB 2048
#define SS 8
#define DNUM 8
#define LL 50
#define EDIM 16
#define FDIM 512
#define HID1 256
#define HID2 128
#define VF 100000
#define KDNN 1216          // 1160 padded to 64-multiple
#define ROWS (BB*LL)       // 102400

// ---------- helpers ----------
__device__ inline u16 f2bf(float x) {            // HW RNE cvt (compiler packs)
    return __builtin_bit_cast(u16, __float2bfloat16(x));
}
__device__ inline float bf2f(u16 b) {
    u32 u = ((u32)b) << 16;
    return __builtin_bit_cast(float, u);
}
__device__ inline void load16_lds(const void* g, void* l) {
    __builtin_amdgcn_global_load_lds(
        (const __attribute__((address_space(1))) u32*)g,
        (__attribute__((address_space(3))) u32*)l, 16, 0, 0);
}
__device__ inline float wave_sum(float v) {
    #pragma unroll
    for (int off = 32; off > 0; off >>= 1) v += __shfl_xor(v, off, 64);
    return v;
}
__device__ inline float wave_max(float v) {
    #pragma unroll
    for (int off = 32; off > 0; off >>= 1) v = fmaxf(v, __shfl_xor(v, off, 64));
    return v;
}
__device__ inline void cvt8(const float4& a, const float4& b, ushort8& o) {
    o[0]=f2bf(a.x); o[1]=f2bf(a.y); o[2]=f2bf(a.z); o[3]=f2bf(a.w);
    o[4]=f2bf(b.x); o[5]=f2bf(b.y); o[6]=f2bf(b.z); o[7]=f2bf(b.w);
}

// ---------- K0 (fused): cvt_table + prep_weights + gather_b ----------
// Block-range dispatch: [0,4096) table cvt (grid-stride), [4096,6208) weight
// prep, [6208,8256) per-b gather. The small parts overlap the BW-bound
// table stream instead of serializing as separate launches.
#define CVT_BLKS 4096
#define PREP_BLKS 2112
__global__ __launch_bounds__(256) void prep_all(
    const float* __restrict__ ft, u16* __restrict__ hb,
    const float* __restrict__ w1, const float* __restrict__ dw1,
    const float* __restrict__ dw2,
    u16* __restrict__ WHP_T, u16* __restrict__ WQ_T,
    u16* __restrict__ W1D_T, u16* __restrict__ W2D_T,
    const int* __restrict__ sparse_ids, const float* __restrict__ dense,
    const int* __restrict__ feedid, const float* __restrict__ emb_tables,
    u16* __restrict__ dnn_in, u16* __restrict__ A_q)
{
    int blk = blockIdx.x, t = threadIdx.x;
    if (blk < CVT_BLKS) {
        // ---- bf16 copy of feed_table (leaves HB L3-resident) ----
        const size_t total = (size_t)VF * FDIM / 8;
        for (size_t i = (size_t)blk * 256 + t; i < total;
             i += (size_t)CVT_BLKS * 256) {
            const float4* s = (const float4*)(ft + i * 8);
            float4 a = s[0], b = s[1];
            ushort8 o; cvt8(a, b, o);
            *(ushort8*)(hb + i * 8) = o;
        }
    } else if (blk < CVT_BLKS + PREP_BLKS) {
        // ---- weight prep (combine + transpose + bf16), all linear ----
        int idx = (blk - CVT_BLKS) * 256 + t;
        if (idx < 131072) {
            int n = idx >> 10, k = idx & 1023;
            float v;
            if (k < 512) v = w1[(512 + k) * 128 + n] - w1[(1024 + k) * 128 + n];
            else         v = w1[(1024 + k) * 128 + n];   // 1536 + (k-512)
            WHP_T[n * 1024 + k] = f2bf(v);
        } else if (idx < 196608) {
            int i = idx - 131072;
            int n = i >> 9, k = i & 511;
            WQ_T[n * 512 + k] = f2bf(w1[k * 128 + n] + w1[(1024 + k) * 128 + n]);
        } else if (idx < 507904) {
            int i = idx - 196608;
            int n = i / KDNN, k = i - n * KDNN;
            W1D_T[i] = (k < 1160) ? f2bf(dw1[k * HID1 + n]) : (u16)0;
        } else if (idx < 540672) {
            int i = idx - 507904;
            int n = i >> 8, k = i & 255;
            W2D_T[i] = f2bf(dw2[k * HID2 + n]);
        }
    } else {
        // ---- per-b gather: sparse emb + dense + feed -> dnn_in, A_q ----
        int b = blk - (CVT_BLKS + PREP_BLKS);
        u16* drow = dnn_in + (size_t)b * KDNN;
        if (t < 128) {
            int s = t >> 4, e = t & 15;
            int id = sparse_ids[b * SS + s];
            float v = emb_tables[(size_t)s * 1600000 + (size_t)id * EDIM + e];
            drow[t] = f2bf(v);
        } else if (t < 136) {
            drow[t] = f2bf(dense[b * DNUM + (t - 128)]);
        } else if (t < 192) {
            drow[1160 + (t - 136)] = 0;   // K padding
        }
        int fid = feedid[b];
        float2 f = *(const float2*)&ft[(size_t)fid * FDIM + t * 2];
        u16 u0 = f2bf(f.x), u1 = f2bf(f.y);
        drow[136 + t * 2] = u0;
        drow[136 + t * 2 + 1] = u1;
        A_q[(size_t)b * FDIM + t * 2] = u0;
        A_q[(size_t)b * FDIM + t * 2 + 1] = u1;
    }
}

// ---------- K2: generic bf16 MFMA GEMM, templated M-tile ----------
template<int BM, bool RELU, bool OUT_BF16>
__global__ __launch_bounds__(256, 4) void gemm_bt(
    const u16* __restrict__ A, int lda,
    const u16* __restrict__ BT, int ldb,
    const float* __restrict__ bias,
    void* __restrict__ Cv, int M, int N, int K)
{
    constexpr int MI = BM / 32;           // frags per wave in M
    __shared__ u16 As[BM * 64];
    __shared__ u16 Bs[128 * 64];
    int m0 = blockIdx.x * BM, n0 = blockIdx.y * 128;
    int tid = threadIdx.x, wave = tid >> 6, lane = tid & 63;
    int lrow = lane >> 3, lk = (lane & 7) * 8;
    f32x4 acc[MI][4];
    f32x4 zz = {0.f, 0.f, 0.f, 0.f};
    #pragma unroll
    for (int i = 0; i < MI; i++)
        #pragma unroll
        for (int j = 0; j < 4; j++) acc[i][j] = zz;
    int wm = (wave >> 1) * (BM / 2), wn = (wave & 1) * 64;

    for (int kt = 0; kt < K; kt += 64) {
        #pragma unroll
        for (int j = 0; j < MI; ++j) {
            int c = wave * MI + j;
            int row = c * 8 + lrow;
            load16_lds(A + (size_t)(m0 + row) * lda + kt + lk, &As[c * 512]);
        }
        #pragma unroll
        for (int j = 0; j < 4; ++j) {
            int c = wave * 4 + j;
            int row = c * 8 + lrow;
            load16_lds(BT + (size_t)(n0 + row) * ldb + kt + lk, &Bs[c * 512]);
        }
        __syncthreads();
        #pragma unroll
        for (int ks = 0; ks < 2; ++ks) {
            int kk = ks * 32 + (lane >> 4) * 8;
            short8 af[MI], bf[4];
            #pragma unroll
            for (int i = 0; i < MI; i++)
                af[i] = *(const short8*)&As[(wm + i * 16 + (lane & 15)) * 64 + kk];
            #pragma unroll
            for (int j = 0; j < 4; j++)
                bf[j] = *(const short8*)&Bs[(wn + j * 16 + (lane & 15)) * 64 + kk];
            #pragma unroll
            for (int i = 0; i < MI; i++)
                #pragma unroll
                for (int j = 0; j < 4; j++)
                    acc[i][j] = __builtin_amdgcn_mfma_f32_16x16x32_bf16(
                        af[i], bf[j], acc[i][j], 0, 0, 0);
        }
        __syncthreads();
    }
    #pragma unroll
    for (int i = 0; i < MI; i++) {
        #pragma unroll
        for (int j = 0; j < 4; j++) {
            #pragma unroll
            for (int r = 0; r < 4; r++) {
                int row = m0 + wm + i * 16 + (lane >> 4) * 4 + r;
                int col = n0 + wn + j * 16 + (lane & 15);
                float v = acc[i][j][r];
                if (bias) v += bias[col];
                if (RELU) v = fmaxf(v, 0.f);
                size_t off = (size_t)row * N + col;
                if (OUT_BF16) ((u16*)Cv)[off] = f2bf(v);
                else ((float*)Cv)[off] = v;
            }
        }
    }
}

// ---------- K3: DIN GEMM v13 — zero-sync k-loop, all operands streamed ----------
// Block = 64 rows x 128 cols, 4 waves (2m x 2n). NO LDS staging, NO barriers
// in the k-loop: h/q frags from HB16 (bf16, L3-resident), B frags DIRECT
// from linear WHP_T (256 KB, L2-resident across all blocks; ~205 MB agg L2
// traffic ~ 6 us). Latency hidden purely by TLP: LDS ~2 KB + VGPR<=84 ->
// 24 waves/CU (vs 16 in R10). Epilogue: score via shfl + one LDS reduce.
__global__ __launch_bounds__(256, 6) void din_gemm(
    const int* __restrict__ hist_ids, const int* __restrict__ feedid,
    const u16* __restrict__ HB,
    const u16* __restrict__ WHP_T,
    const float* __restrict__ qw, const float* __restrict__ b1,
    const float* __restrict__ w2v, float* __restrict__ scores)
{
    __shared__ float qbs[3 * 128];    // qw + b1
    __shared__ float w2s[128];
    __shared__ float sred[64 * 2];

    int t = threadIdx.x, w = t >> 6, lane = t & 63;
    int m0 = blockIdx.x * 64;
    int b0 = m0 / LL;
    int fr = lane & 15, kg = (lane >> 4) * 8;
    int wm = (w >> 1) * 32, wn = (w & 1) * 64;

    // ---- prologue: qw+b1, w2 into LDS ----
    for (int idx = t; idx < 384; idx += 256) {
        int bi = idx >> 7, col = idx & 127;
        int bb = b0 + bi; if (bb > BB - 1) bb = BB - 1;
        qbs[idx] = qw[bb * 128 + col] + b1[col];
    }
    if (t < 128) w2s[t] = w2v[t];

    // ---- per-frag pointers (registers) ----
    const u16* hp[2];
    const u16* qp[2];
    #pragma unroll
    for (int i = 0; i < 2; ++i) {
        int gr = m0 + wm + i * 16 + fr;
        hp[i] = HB + (size_t)hist_ids[gr] * FDIM + kg;
        qp[i] = HB + (size_t)feedid[gr / LL] * FDIM + kg;
    }
    const u16* bp_[4];
    #pragma unroll
    for (int j = 0; j < 4; ++j)
        bp_[j] = WHP_T + (size_t)(wn + j * 16 + fr) * 1024 + kg;

    f32x4 acc[2][4];
    f32x4 zz = {0.f, 0.f, 0.f, 0.f};
    #pragma unroll
    for (int i = 0; i < 2; i++)
        #pragma unroll
        for (int j = 0; j < 4; j++) acc[i][j] = zz;

    // ---- free-running k-loop (no barriers, no LDS writes) ----
    #pragma unroll 2
    for (int ks = 0; ks < 16; ++ks) {
        short8 bh[4], bpv[4];
        #pragma unroll
        for (int j = 0; j < 4; ++j) {
            bh[j]  = *(const short8*)(bp_[j] + ks * 32);
            bpv[j] = *(const short8*)(bp_[j] + 512 + ks * 32);
        }
        short8 ah[2], ap[2];
        #pragma unroll
        for (int i = 0; i < 2; ++i) {
            ushort8 hv = *(const ushort8*)(hp[i] + ks * 32);
            ushort8 qv = *(const ushort8*)(qp[i] + ks * 32);
            ushort8 pv;
            #pragma unroll
            for (int e = 0; e < 8; ++e)
                pv[e] = f2bf(bf2f(hv[e]) * bf2f(qv[e]));
            ah[i] = __builtin_bit_cast(short8, hv);
            ap[i] = __builtin_bit_cast(short8, pv);
        }
        #pragma unroll
        for (int i = 0; i < 2; ++i)
            #pragma unroll
            for (int j = 0; j < 4; ++j) {
                acc[i][j] = __builtin_amdgcn_mfma_f32_16x16x32_bf16(
                    ah[i], bh[j], acc[i][j], 0, 0, 0);
                acc[i][j] = __builtin_amdgcn_mfma_f32_16x16x32_bf16(
                    ap[i], bpv[j], acc[i][j], 0, 0, 0);
            }
    }

    // ---- epilogue: score[row] = sum_col relu(acc + qw + b1) * w2 ----
    #pragma unroll
    for (int i = 0; i < 2; ++i) {
        #pragma unroll
        for (int r = 0; r < 4; ++r) {
            int rl = wm + i * 16 + (lane >> 4) * 4 + r;
            int bi = (m0 + rl) / LL - b0;
            float s = 0.f;
            #pragma unroll
            for (int j = 0; j < 4; ++j) {
                int col = wn + j * 16 + fr;
                float v = acc[i][j][r] + qbs[bi * 128 + col];
                s += fmaxf(v, 0.f) * w2s[col];
            }
            s += __shfl_xor(s, 1, 64);
            s += __shfl_xor(s, 2, 64);
            s += __shfl_xor(s, 4, 64);
            s += __shfl_xor(s, 8, 64);
            if (fr == 0) sred[rl * 2 + (w & 1)] = s;
        }
    }
    __syncthreads();
    if (t < 64) scores[m0 + t] = sred[t * 2] + sred[t * 2 + 1];
}

// ---------- K4: softmax over L + user_interest (bf16 table, L3-hot) ----------
__global__ __launch_bounds__(256) void softmax_ui(
    const float* __restrict__ scores, const int* __restrict__ hist_ids,
    const u16* __restrict__ HB, u16* __restrict__ dnn_in)
{
    int b = blockIdx.x, t = threadIdx.x;
    int wave = t >> 6, lane = t & 63;
    __shared__ float sc[56];
    __shared__ int hid[56];
    if (t >= 64 && t < 64 + LL) hid[t - 64] = hist_ids[b * LL + (t - 64)];
    if (wave == 0) {
        float x = (lane < LL) ? scores[b * LL + lane] : -1e30f;
        float mx = wave_max(x);
        float e = (lane < LL) ? __expf(x - mx) : 0.f;
        float s = wave_sum(e);
        if (lane < LL) sc[lane] = e / s;
    }
    __syncthreads();
    int d = t * 2;
    float a0 = 0.f, a1 = 0.f;
    #pragma unroll 5
    for (int l = 0; l < LL; ++l) {
        u32 v = *(const u32*)(HB + (size_t)hid[l] * FDIM + d);
        float al = sc[l];
        a0 += al * bf2f((u16)(v & 0xffff));
        a1 += al * bf2f((u16)(v >> 16));
    }
    dnn_in[(size_t)b * KDNN + 648 + d] = f2bf(a0);
    dnn_in[(size_t)b * KDNN + 648 + d + 1] = f2bf(a1);
}

// ---------- K5: MMOE + task heads ----------
__global__ __launch_bounds__(256) void mmoe_head(
    const float* __restrict__ dnn_out, const float* __restrict__ expert_w,
    const float* __restrict__ gate_w, const float* __restrict__ out_w,
    const float* __restrict__ out_b, float* __restrict__ out)
{
    int wave = threadIdx.x >> 6, lane = threadIdx.x & 63;
    int b = blockIdx.x * 4 + wave;
    __shared__ float ds[4][128];
    __shared__ float eo[4][64];
    __shared__ float gt[4][32];
    ds[wave][lane] = dnn_out[b * 128 + lane];
    ds[wave][lane + 64] = dnn_out[b * 128 + 64 + lane];
    __syncthreads();
    int e = lane >> 3, o = lane & 7;
    float acc = 0.f;
    for (int k = 0; k < 128; ++k)
        acc += ds[wave][k] * expert_w[(e * 128 + k) * 8 + o];
    eo[wave][lane] = acc;
    if (lane < 32) {
        int tt = lane >> 3, ee = lane & 7;
        float g = 0.f;
        for (int k = 0; k < 128; ++k)
            g += ds[wave][k] * gate_w[(tt * 128 + k) * 8 + ee];
        float m = g;
        #pragma unroll
        for (int off = 4; off; off >>= 1) m = fmaxf(m, __shfl_xor(m, off, 8));
        float ex = __expf(g - m);
        float s = ex;
        #pragma unroll
        for (int off = 4; off; off >>= 1) s += __shfl_xor(s, off, 8);
        gt[wave][lane] = ex / s;
    }
    __syncthreads();
    if (lane < 32) {
        int tt = lane >> 3, o2 = lane & 7;
        float to = 0.f;
        #pragma unroll
        for (int ee = 0; ee < 8; ++ee)
            to += gt[wave][tt * 8 + ee] * eo[wave][ee * 8 + o2];
        float pl = to * out_w[tt * 8 + o2];
        #pragma unroll
        for (int off = 4; off; off >>= 1) pl += __shfl_xor(pl, off, 8);
        if (o2 == 0) {
            float logit = pl + out_b[tt];
            out[b * 4 + tt] = 1.f / (1.f + __expf(-logit));
        }
    }
}

// ---------- host ----------
extern "C" void kernel_launch(void* const* d_in, const int* in_sizes, int n_in,
                              void* d_out, int out_size, void* d_ws, size_t ws_size,
                              hipStream_t stream)
{
    const int*   sparse_ids = (const int*)d_in[0];
    const float* dense      = (const float*)d_in[1];
    const int*   feedid     = (const int*)d_in[2];
    const int*   hist_ids   = (const int*)d_in[3];
    const float* emb_tables = (const float*)d_in[4];
    const float* feed_table = (const float*)d_in[5];
    const float* attn_w1    = (const float*)d_in[6];
    const float* attn_b1    = (const float*)d_in[7];
    const float* attn_w2    = (const float*)d_in[8];
    const float* attn_b2    = (const float*)d_in[9];
    const float* dnn_w1     = (const float*)d_in[10];
    const float* dnn_b1     = (const float*)d_in[11];
    const float* dnn_w2     = (const float*)d_in[12];
    const float* dnn_b2     = (const float*)d_in[13];
    const float* expert_w   = (const float*)d_in[14];
    const float* gate_w     = (const float*)d_in[15];
    const float* out_w      = (const float*)d_in[16];
    const float* out_b      = (const float*)d_in[17];
    float* out = (float*)d_out;

    char* ws = (char*)d_ws;
    size_t off = 0;
    auto alloc = [&](size_t bytes) {
        char* p = ws + off;
        off += (bytes + 255) & ~(size_t)255;
        return p;
    };
    u16* WHP_T = (u16*)alloc(131072 * 2);
    u16* WQ_T  = (u16*)alloc(65536 * 2);
    u16* W1D_T = (u16*)alloc((size_t)HID1 * KDNN * 2);
    u16* W2D_T = (u16*)alloc((size_t)HID2 * HID1 * 2);
    u16* AQ    = (u16*)alloc((size_t)BB * FDIM * 2);
    float* QW  = (float*)alloc((size_t)BB * 128 * 4);
    u16* DNNIN = (u16*)alloc((size_t)BB * KDNN * 2);
    u16* Z     = (u16*)alloc((size_t)BB * HID1 * 2);
    float* DOUT= (float*)alloc((size_t)BB * HID2 * 4);
    float* SCORES = (float*)alloc((size_t)ROWS * 4);
    u16* HB16  = (u16*)alloc((size_t)VF * FDIM * 2);   // 102.4 MB

    prep_all<<<CVT_BLKS + PREP_BLKS + BB, 256, 0, stream>>>(
        feed_table, HB16, attn_w1, dnn_w1, dnn_w2,
        WHP_T, WQ_T, W1D_T, W2D_T,
        sparse_ids, dense, feedid, emb_tables, DNNIN, AQ);
    gemm_bt<32, false, false><<<dim3(BB / 32, 1), 256, 0, stream>>>(
        AQ, 512, WQ_T, 512, nullptr, QW, BB, 128, 512);
    din_gemm<<<ROWS / 64, 256, 0, stream>>>(
        hist_ids, feedid, HB16, WHP_T, QW, attn_b1, attn_w2, SCORES);
    softmax_ui<<<BB, 256, 0, stream>>>(SCORES, hist_ids, HB16, DNNIN);
    gemm_bt<32, true, true><<<dim3(BB / 32, HID1 / 128), 256, 0, stream>>>(
        DNNIN, KDNN, W1D_T, KDNN, dnn_b1, Z, BB, HID1, KDNN);
    gemm_bt<32, true, false><<<dim3(BB / 32, 1), 256, 0, stream>>>(
        Z, HID1, W2D_T, HID1, dnn_b2, DOUT, BB, HID2, HID1);
    mmoe_head<<<BB / 4, 256, 0, stream>>>(DOUT, expert_w, gate_w, out_w,
                                          out_b, out);
}

// Round 13
// 237.564 us; speedup vs baseline: 1.4424x; 1.4424x over previous
//
#include <hip/hip_runtime.h>
#include <hip/hip_bf16.h>

typedef unsigned short u16;
typedef unsigned int u32;
typedef __attribute__((ext_vector_type(8))) short short8;   // 8 bf16 for MFMA frags
typedef __attribute__((ext_vector_type(8))) u16 ushort8;
typedef __attribute__((ext_vector_type(4))) float f32x4;

// ---------- constants ----------
#define BB 2048
#define SS 8
#define DNUM 8
#define LL 50
#define EDIM 16
#define FDIM 512
#define HID1 256
#define HID2 128
#define VF 100000
#define KDNN 1216          // 1160 padded to 64-multiple
#define ROWS (BB*LL)       // 102400

// ---------- helpers ----------
__device__ inline u16 f2bf(float x) {            // HW RNE cvt (compiler packs)
    return __builtin_bit_cast(u16, __float2bfloat16(x));
}
__device__ inline float bf2f(u16 b) {
    u32 u = ((u32)b) << 16;
    return __builtin_bit_cast(float, u);
}
__device__ inline void load16_lds(const void* g, void* l) {
    __builtin_amdgcn_global_load_lds(
        (const __attribute__((address_space(1))) u32*)g,
        (__attribute__((address_space(3))) u32*)l, 16, 0, 0);
}
__device__ inline float wave_sum(float v) {
    #pragma unroll
    for (int off = 32; off > 0; off >>= 1) v += __shfl_xor(v, off, 64);
    return v;
}
__device__ inline float wave_max(float v) {
    #pragma unroll
    for (int off = 32; off > 0; off >>= 1) v = fmaxf(v, __shfl_xor(v, off, 64));
    return v;
}
__device__ inline void cvt8(const float4& a, const float4& b, ushort8& o) {
    o[0]=f2bf(a.x); o[1]=f2bf(a.y); o[2]=f2bf(a.z); o[3]=f2bf(a.w);
    o[4]=f2bf(b.x); o[5]=f2bf(b.y); o[6]=f2bf(b.z); o[7]=f2bf(b.w);
}

// ---------- K-2: zero used-row flags (re-zeroed every call: determinism) ----------
__global__ __launch_bounds__(256) void zero_flags(u32* __restrict__ f) {
    int i = blockIdx.x * 256 + threadIdx.x;
    if (i < 25024) f[i] = 0;          // 100096 bytes
}

// ---------- K-1: mark rows referenced by hist_ids / feedid ----------
__global__ __launch_bounds__(256) void mark_used(
    const int* __restrict__ hist, const int* __restrict__ feedid,
    unsigned char* __restrict__ flags)
{
    int i = blockIdx.x * 256 + threadIdx.x;
    if (i < ROWS) flags[hist[i]] = 1;
    if (i < BB) flags[feedid[i]] = 1;
}

// ---------- K0 (fused): dedup'd cvt + weight prep + per-b gather ----------
// [0,25000): flag-gated bf16 cvt of feed_table rows (4 rows/block; ~65% of
// rows used -> ~131MB read vs 205). [25000,27112): weight prep (WHP_T
// LINEAR [128n][1024k]: k<512 Wh=W1b-W1c, else Wp=W1d; WQ_T; W1D_T; W2D_T).
// [27112,29160): per-b gather -> dnn_in, A_q.
#define CVT_BLKS 25000
#define PREP_BLKS 2112
__global__ __launch_bounds__(256) void prep_all(
    const float* __restrict__ ft, u16* __restrict__ hb,
    const unsigned char* __restrict__ flags,
    const float* __restrict__ w1, const float* __restrict__ dw1,
    const float* __restrict__ dw2,
    u16* __restrict__ WHP_T, u16* __restrict__ WQ_T,
    u16* __restrict__ W1D_T, u16* __restrict__ W2D_T,
    const int* __restrict__ sparse_ids, const float* __restrict__ dense,
    const int* __restrict__ feedid, const float* __restrict__ emb_tables,
    u16* __restrict__ dnn_in, u16* __restrict__ A_q)
{
    int blk = blockIdx.x, t = threadIdx.x;
    if (blk < CVT_BLKS) {
        int r = blk * 4 + (t >> 6);
        if (flags[r]) {
            const float* src = ft + (size_t)r * FDIM + (t & 63) * 8;
            float4 a = *(const float4*)src;
            float4 b = *(const float4*)(src + 4);
            ushort8 o; cvt8(a, b, o);
            *(ushort8*)(hb + (size_t)r * FDIM + (t & 63) * 8) = o;
        }
    } else if (blk < CVT_BLKS + PREP_BLKS) {
        int idx = (blk - CVT_BLKS) * 256 + t;
        if (idx < 131072) {
            int n = idx >> 10, k = idx & 1023;
            float v;
            if (k < 512) v = w1[(512 + k) * 128 + n] - w1[(1024 + k) * 128 + n];
            else         v = w1[(1024 + k) * 128 + n];   // 1536 + (k-512)
            WHP_T[n * 1024 + k] = f2bf(v);
        } else if (idx < 196608) {
            int i = idx - 131072;
            int n = i >> 9, k = i & 511;
            WQ_T[n * 512 + k] = f2bf(w1[k * 128 + n] + w1[(1024 + k) * 128 + n]);
        } else if (idx < 507904) {
            int i = idx - 196608;
            int n = i / KDNN, k = i - n * KDNN;
            W1D_T[i] = (k < 1160) ? f2bf(dw1[k * HID1 + n]) : (u16)0;
        } else if (idx < 540672) {
            int i = idx - 507904;
            int n = i >> 8, k = i & 255;
            W2D_T[i] = f2bf(dw2[k * HID2 + n]);
        }
    } else {
        int b = blk - (CVT_BLKS + PREP_BLKS);
        u16* drow = dnn_in + (size_t)b * KDNN;
        if (t < 128) {
            int s = t >> 4, e = t & 15;
            int id = sparse_ids[b * SS + s];
            float v = emb_tables[(size_t)s * 1600000 + (size_t)id * EDIM + e];
            drow[t] = f2bf(v);
        } else if (t < 136) {
            drow[t] = f2bf(dense[b * DNUM + (t - 128)]);
        } else if (t < 192) {
            drow[1160 + (t - 136)] = 0;   // K padding
        }
        int fid = feedid[b];
        float2 f = *(const float2*)&ft[(size_t)fid * FDIM + t * 2];
        u16 u0 = f2bf(f.x), u1 = f2bf(f.y);
        drow[136 + t * 2] = u0;
        drow[136 + t * 2 + 1] = u1;
        A_q[(size_t)b * FDIM + t * 2] = u0;
        A_q[(size_t)b * FDIM + t * 2 + 1] = u1;
    }
}

// ---------- K2: generic bf16 MFMA GEMM, templated M-tile ----------
template<int BM, bool RELU, bool OUT_BF16>
__global__ __launch_bounds__(256, 4) void gemm_bt(
    const u16* __restrict__ A, int lda,
    const u16* __restrict__ BT, int ldb,
    const float* __restrict__ bias,
    void* __restrict__ Cv, int M, int N, int K)
{
    constexpr int MI = BM / 32;           // frags per wave in M
    __shared__ u16 As[BM * 64];
    __shared__ u16 Bs[128 * 64];
    int m0 = blockIdx.x * BM, n0 = blockIdx.y * 128;
    int tid = threadIdx.x, wave = tid >> 6, lane = tid & 63;
    int lrow = lane >> 3, lk = (lane & 7) * 8;
    f32x4 acc[MI][4];
    f32x4 zz = {0.f, 0.f, 0.f, 0.f};
    #pragma unroll
    for (int i = 0; i < MI; i++)
        #pragma unroll
        for (int j = 0; j < 4; j++) acc[i][j] = zz;
    int wm = (wave >> 1) * (BM / 2), wn = (wave & 1) * 64;

    for (int kt = 0; kt < K; kt += 64) {
        #pragma unroll
        for (int j = 0; j < MI; ++j) {
            int c = wave * MI + j;
            int row = c * 8 + lrow;
            load16_lds(A + (size_t)(m0 + row) * lda + kt + lk, &As[c * 512]);
        }
        #pragma unroll
        for (int j = 0; j < 4; ++j) {
            int c = wave * 4 + j;
            int row = c * 8 + lrow;
            load16_lds(BT + (size_t)(n0 + row) * ldb + kt + lk, &Bs[c * 512]);
        }
        __syncthreads();
        #pragma unroll
        for (int ks = 0; ks < 2; ++ks) {
            int kk = ks * 32 + (lane >> 4) * 8;
            short8 af[MI], bf[4];
            #pragma unroll
            for (int i = 0; i < MI; i++)
                af[i] = *(const short8*)&As[(wm + i * 16 + (lane & 15)) * 64 + kk];
            #pragma unroll
            for (int j = 0; j < 4; j++)
                bf[j] = *(const short8*)&Bs[(wn + j * 16 + (lane & 15)) * 64 + kk];
            #pragma unroll
            for (int i = 0; i < MI; i++)
                #pragma unroll
                for (int j = 0; j < 4; j++)
                    acc[i][j] = __builtin_amdgcn_mfma_f32_16x16x32_bf16(
                        af[i], bf[j], acc[i][j], 0, 0, 0);
        }
        __syncthreads();
    }
    #pragma unroll
    for (int i = 0; i < MI; i++) {
        #pragma unroll
        for (int j = 0; j < 4; j++) {
            #pragma unroll
            for (int r = 0; r < 4; r++) {
                int row = m0 + wm + i * 16 + (lane >> 4) * 4 + r;
                int col = n0 + wn + j * 16 + (lane & 15);
                float v = acc[i][j][r];
                if (bias) v += bias[col];
                if (RELU) v = fmaxf(v, 0.f);
                size_t off = (size_t)row * N + col;
                if (OUT_BF16) ((u16*)Cv)[off] = f2bf(v);
                else ((float*)Cv)[off] = v;
            }
        }
    }
}

#define MFMA_BF16 __builtin_amdgcn_mfma_f32_16x16x32_bf16

// ---------- K3: DIN GEMM v14 — free-running, manual register prefetch ----------
// Block = 64 rows x 128 cols, 4 waves (2m x 2n, wave tile 32x64). ZERO
// k-loop barriers / LDS staging. h: depth-2 prefetch in named regs (L3
// ~600cyc covered by 2 compute phases). B h-stream: depth-1 (L2 ~200cyc).
// q + B p-stream: loaded at compute, hidden under the 8 h-stream MFMAs.
// R12 lesson: without manual prefetch hipcc emits a 40-VGPR serial
// schedule; R8 proved named-buffer prefetch IS honored.
__global__ __launch_bounds__(256, 3) void din_gemm(
    const int* __restrict__ hist_ids, const int* __restrict__ feedid,
    const u16* __restrict__ HB, const u16* __restrict__ WHP_T,
    const float* __restrict__ qw, const float* __restrict__ b1,
    const float* __restrict__ w2v, float* __restrict__ scores)
{
    __shared__ float qbs[3 * 128];
    __shared__ float w2s[128];
    __shared__ float sred[64 * 2];

    int t = threadIdx.x, w = t >> 6, lane = t & 63;
    int m0 = blockIdx.x * 64, b0 = m0 / LL;
    int fr = lane & 15, kg = (lane >> 4) * 8;
    int wm = (w >> 1) * 32, wn = (w & 1) * 64;

    // ---- prologue: qw+b1, w2 into LDS (barrier deferred to epilogue) ----
    for (int idx = t; idx < 384; idx += 256) {
        int bi = idx >> 7, col = idx & 127;
        int bb = b0 + bi; if (bb > BB - 1) bb = BB - 1;
        qbs[idx] = qw[bb * 128 + col] + b1[col];
    }
    if (t < 128) w2s[t] = w2v[t];

    int gr0 = m0 + wm + fr, gr1 = gr0 + 16;
    const u16* hp0 = HB + (size_t)hist_ids[gr0] * FDIM + kg;
    const u16* hp1 = HB + (size_t)hist_ids[gr1] * FDIM + kg;
    const u16* qp0 = HB + (size_t)feedid[gr0 / LL] * FDIM + kg;
    const u16* qp1 = HB + (size_t)feedid[gr1 / LL] * FDIM + kg;
    const u16* bp0 = WHP_T + (size_t)(wn + fr) * 1024 + kg;

    f32x4 acc[2][4];
    f32x4 zz = {0.f, 0.f, 0.f, 0.f};
    #pragma unroll
    for (int i = 0; i < 2; i++)
        #pragma unroll
        for (int j = 0; j < 4; j++) acc[i][j] = zz;

    // ---- prefetch preload: h for ks=0,1 ; B h-stream for ks=0 ----
    ushort8 hA0 = *(const ushort8*)(hp0);
    ushort8 hA1 = *(const ushort8*)(hp1);
    ushort8 hB0 = *(const ushort8*)(hp0 + 32);
    ushort8 hB1 = *(const ushort8*)(hp1 + 32);
    short8 wA0 = *(const short8*)(bp0);
    short8 wA1 = *(const short8*)(bp0 + 16 * 1024);
    short8 wA2 = *(const short8*)(bp0 + 32 * 1024);
    short8 wA3 = *(const short8*)(bp0 + 48 * 1024);
    short8 wB0, wB1, wB2, wB3;

#define DIN_STEP(ks, HC0, HC1, W0, W1, W2, W3, WN0, WN1, WN2, WN3)           \
    {                                                                         \
        ushort8 hv0 = HC0, hv1 = HC1;                                         \
        if ((ks) + 2 < 16) {                                                  \
            HC0 = *(const ushort8*)(hp0 + ((ks) + 2) * 32);                   \
            HC1 = *(const ushort8*)(hp1 + ((ks) + 2) * 32);                   \
        }                                                                     \
        if ((ks) + 1 < 16) {                                                  \
            WN0 = *(const short8*)(bp0 + ((ks) + 1) * 32);                    \
            WN1 = *(const short8*)(bp0 + 16 * 1024 + ((ks) + 1) * 32);        \
            WN2 = *(const short8*)(bp0 + 32 * 1024 + ((ks) + 1) * 32);        \
            WN3 = *(const short8*)(bp0 + 48 * 1024 + ((ks) + 1) * 32);        \
        }                                                                     \
        ushort8 qv0 = *(const ushort8*)(qp0 + (ks) * 32);                     \
        ushort8 qv1 = *(const ushort8*)(qp1 + (ks) * 32);                     \
        short8 wp0 = *(const short8*)(bp0 + 512 + (ks) * 32);                 \
        short8 wp1 = *(const short8*)(bp0 + 16 * 1024 + 512 + (ks) * 32);     \
        short8 wp2 = *(const short8*)(bp0 + 32 * 1024 + 512 + (ks) * 32);     \
        short8 wp3 = *(const short8*)(bp0 + 48 * 1024 + 512 + (ks) * 32);     \
        short8 ah0 = __builtin_bit_cast(short8, hv0);                         \
        short8 ah1 = __builtin_bit_cast(short8, hv1);                         \
        acc[0][0] = MFMA_BF16(ah0, W0, acc[0][0], 0, 0, 0);                   \
        acc[0][1] = MFMA_BF16(ah0, W1, acc[0][1], 0, 0, 0);                   \
        acc[0][2] = MFMA_BF16(ah0, W2, acc[0][2], 0, 0, 0);                   \
        acc[0][3] = MFMA_BF16(ah0, W3, acc[0][3], 0, 0, 0);                   \
        acc[1][0] = MFMA_BF16(ah1, W0, acc[1][0], 0, 0, 0);                   \
        acc[1][1] = MFMA_BF16(ah1, W1, acc[1][1], 0, 0, 0);                   \
        acc[1][2] = MFMA_BF16(ah1, W2, acc[1][2], 0, 0, 0);                   \
        acc[1][3] = MFMA_BF16(ah1, W3, acc[1][3], 0, 0, 0);                   \
        ushort8 pv0, pv1;                                                     \
        _Pragma("unroll")                                                     \
        for (int e = 0; e < 8; ++e) {                                         \
            pv0[e] = f2bf(bf2f(hv0[e]) * bf2f(qv0[e]));                       \
            pv1[e] = f2bf(bf2f(hv1[e]) * bf2f(qv1[e]));                       \
        }                                                                     \
        short8 ap0 = __builtin_bit_cast(short8, pv0);                         \
        short8 ap1 = __builtin_bit_cast(short8, pv1);                         \
        acc[0][0] = MFMA_BF16(ap0, wp0, acc[0][0], 0, 0, 0);                  \
        acc[0][1] = MFMA_BF16(ap0, wp1, acc[0][1], 0, 0, 0);                  \
        acc[0][2] = MFMA_BF16(ap0, wp2, acc[0][2], 0, 0, 0);                  \
        acc[0][3] = MFMA_BF16(ap0, wp3, acc[0][3], 0, 0, 0);                  \
        acc[1][0] = MFMA_BF16(ap1, wp0, acc[1][0], 0, 0, 0);                  \
        acc[1][1] = MFMA_BF16(ap1, wp1, acc[1][1], 0, 0, 0);                  \
        acc[1][2] = MFMA_BF16(ap1, wp2, acc[1][2], 0, 0, 0);                  \
        acc[1][3] = MFMA_BF16(ap1, wp3, acc[1][3], 0, 0, 0);                  \
    }

    #pragma unroll
    for (int k2 = 0; k2 < 8; ++k2) {
        DIN_STEP(2 * k2,     hA0, hA1, wA0, wA1, wA2, wA3, wB0, wB1, wB2, wB3);
        DIN_STEP(2 * k2 + 1, hB0, hB1, wB0, wB1, wB2, wB3, wA0, wA1, wA2, wA3);
    }
#undef DIN_STEP

    __syncthreads();   // qbs/w2s visible for epilogue

    // ---- epilogue: score[row] = sum_col relu(acc + qw + b1) * w2 ----
    #pragma unroll
    for (int i = 0; i < 2; ++i) {
        #pragma unroll
        for (int r = 0; r < 4; ++r) {
            int rl = wm + i * 16 + (lane >> 4) * 4 + r;
            int bi = (m0 + rl) / LL - b0;
            float s = 0.f;
            #pragma unroll
            for (int j = 0; j < 4; ++j) {
                int col = wn + j * 16 + fr;
                float v = acc[i][j][r] + qbs[bi * 128 + col];
                s += fmaxf(v, 0.f) * w2s[col];
            }
            s += __shfl_xor(s, 1, 64);
            s += __shfl_xor(s, 2, 64);
            s += __shfl_xor(s, 4, 64);
            s += __shfl_xor(s, 8, 64);
            if (fr == 0) sred[rl * 2 + (w & 1)] = s;
        }
    }
    __syncthreads();
    if (t < 64) scores[m0 + t] = sred[t * 2] + sred[t * 2 + 1];
}

// ---------- K4: softmax over L + user_interest (bf16 table, L3-hot) ----------
__global__ __launch_bounds__(256) void softmax_ui(
    const float* __restrict__ scores, const int* __restrict__ hist_ids,
    const u16* __restrict__ HB, u16* __restrict__ dnn_in)
{
    int b = blockIdx.x, t = threadIdx.x;
    int wave = t >> 6, lane = t & 63;
    __shared__ float sc[56];
    __shared__ int hid[56];
    if (t >= 64 && t < 64 + LL) hid[t - 64] = hist_ids[b * LL + (t - 64)];
    if (wave == 0) {
        float x = (lane < LL) ? scores[b * LL + lane] : -1e30f;
        float mx = wave_max(x);
        float e = (lane < LL) ? __expf(x - mx) : 0.f;
        float s = wave_sum(e);
        if (lane < LL) sc[lane] = e / s;
    }
    __syncthreads();
    int d = t * 2;
    float a0 = 0.f, a1 = 0.f;
    #pragma unroll 5
    for (int l = 0; l < LL; ++l) {
        u32 v = *(const u32*)(HB + (size_t)hid[l] * FDIM + d);
        float al = sc[l];
        a0 += al * bf2f((u16)(v & 0xffff));
        a1 += al * bf2f((u16)(v >> 16));
    }
    dnn_in[(size_t)b * KDNN + 648 + d] = f2bf(a0);
    dnn_in[(size_t)b * KDNN + 648 + d + 1] = f2bf(a1);
}

// ---------- K5: MMOE + task heads ----------
__global__ __launch_bounds__(256) void mmoe_head(
    const float* __restrict__ dnn_out, const float* __restrict__ expert_w,
    const float* __restrict__ gate_w, const float* __restrict__ out_w,
    const float* __restrict__ out_b, float* __restrict__ out)
{
    int wave = threadIdx.x >> 6, lane = threadIdx.x & 63;
    int b = blockIdx.x * 4 + wave;
    __shared__ float ds[4][128];
    __shared__ float eo[4][64];
    __shared__ float gt[4][32];
    ds[wave][lane] = dnn_out[b * 128 + lane];
    ds[wave][lane + 64] = dnn_out[b * 128 + 64 + lane];
    __syncthreads();
    int e = lane >> 3, o = lane & 7;
    float acc = 0.f;
    for (int k = 0; k < 128; ++k)
        acc += ds[wave][k] * expert_w[(e * 128 + k) * 8 + o];
    eo[wave][lane] = acc;
    if (lane < 32) {
        int tt = lane >> 3, ee = lane & 7;
        float g = 0.f;
        for (int k = 0; k < 128; ++k)
            g += ds[wave][k] * gate_w[(tt * 128 + k) * 8 + ee];
        float m = g;
        #pragma unroll
        for (int off = 4; off; off >>= 1) m = fmaxf(m, __shfl_xor(m, off, 8));
        float ex = __expf(g - m);
        float s = ex;
        #pragma unroll
        for (int off = 4; off; off >>= 1) s += __shfl_xor(s, off, 8);
        gt[wave][lane] = ex / s;
    }
    __syncthreads();
    if (lane < 32) {
        int tt = lane >> 3, o2 = lane & 7;
        float to = 0.f;
        #pragma unroll
        for (int ee = 0; ee < 8; ++ee)
            to += gt[wave][tt * 8 + ee] * eo[wave][ee * 8 + o2];
        float pl = to * out_w[tt * 8 + o2];
        #pragma unroll
        for (int off = 4; off; off >>= 1) pl += __shfl_xor(pl, off, 8);
        if (o2 == 0) {
            float logit = pl + out_b[tt];
            out[b * 4 + tt] = 1.f / (1.f + __expf(-logit));
        }
    }
}

// ---------- host ----------
extern "C" void kernel_launch(void* const* d_in, const int* in_sizes, int n_in,
                              void* d_out, int out_size, void* d_ws, size_t ws_size,
                              hipStream_t stream)
{
    const int*   sparse_ids = (const int*)d_in[0];
    const float* dense      = (const float*)d_in[1];
    const int*   feedid     = (const int*)d_in[2];
    const int*   hist_ids   = (const int*)d_in[3];
    const float* emb_tables = (const float*)d_in[4];
    const float* feed_table = (const float*)d_in[5];
    const float* attn_w1    = (const float*)d_in[6];
    const float* attn_b1    = (const float*)d_in[7];
    const float* attn_w2    = (const float*)d_in[8];
    const float* attn_b2    = (const float*)d_in[9];
    const float* dnn_w1     = (const float*)d_in[10];
    const float* dnn_b1     = (const float*)d_in[11];
    const float* dnn_w2     = (const float*)d_in[12];
    const float* dnn_b2     = (const float*)d_in[13];
    const float* expert_w   = (const float*)d_in[14];
    const float* gate_w     = (const float*)d_in[15];
    const float* out_w      = (const float*)d_in[16];
    const float* out_b      = (const float*)d_in[17];
    float* out = (float*)d_out;

    char* ws = (char*)d_ws;
    size_t off = 0;
    auto alloc = [&](size_t bytes) {
        char* p = ws + off;
        off += (bytes + 255) & ~(size_t)255;
        return p;
    };
    u16* WHP_T = (u16*)alloc(131072 * 2);
    u16* WQ_T  = (u16*)alloc(65536 * 2);
    u16* W1D_T = (u16*)alloc((size_t)HID1 * KDNN * 2);
    u16* W2D_T = (u16*)alloc((size_t)HID2 * HID1 * 2);
    u16* AQ    = (u16*)alloc((size_t)BB * FDIM * 2);
    float* QW  = (float*)alloc((size_t)BB * 128 * 4);
    u16* DNNIN = (u16*)alloc((size_t)BB * KDNN * 2);
    u16* Z     = (u16*)alloc((size_t)BB * HID1 * 2);
    float* DOUT= (float*)alloc((size_t)BB * HID2 * 4);
    float* SCORES = (float*)alloc((size_t)ROWS * 4);
    unsigned char* FLAGS = (unsigned char*)alloc(100096);
    u16* HB16  = (u16*)alloc((size_t)VF * FDIM * 2);   // 102.4 MB

    zero_flags<<<98, 256, 0, stream>>>((u32*)FLAGS);
    mark_used<<<400, 256, 0, stream>>>(hist_ids, feedid, FLAGS);
    prep_all<<<CVT_BLKS + PREP_BLKS + BB, 256, 0, stream>>>(
        feed_table, HB16, FLAGS, attn_w1, dnn_w1, dnn_w2,
        WHP_T, WQ_T, W1D_T, W2D_T,
        sparse_ids, dense, feedid, emb_tables, DNNIN, AQ);
    gemm_bt<32, false, false><<<dim3(BB / 32, 1), 256, 0, stream>>>(
        AQ, 512, WQ_T, 512, nullptr, QW, BB, 128, 512);
    din_gemm<<<ROWS / 64, 256, 0, stream>>>(
        hist_ids, feedid, HB16, WHP_T, QW, attn_b1, attn_w2, SCORES);
    softmax_ui<<<BB, 256, 0, stream>>>(SCORES, hist_ids, HB16, DNNIN);
    gemm_bt<32, true, true><<<dim3(BB / 32, HID1 / 128), 256, 0, stream>>>(
        DNNIN, KDNN, W1D_T, KDNN, dnn_b1, Z, BB, HID1, KDNN);
    gemm_bt<32, true, false><<<dim3(BB / 32, 1), 256, 0, stream>>>(
        Z, HID1, W2D_T, HID1, dnn_b2, DOUT, BB, HID2, HID1);
    mmoe_head<<<BB / 4, 256, 0, stream>>>(DOUT, expert_w, gate_w, out_w,
                                          out_b, out);
}

// Round 14
// 157.574 us; speedup vs baseline: 2.1747x; 1.5076x over previous
//
#include <hip/hip_runtime.h>
#include <hip/hip_bf16.h>

typedef unsigned short u16;
typedef unsigned int u32;
typedef __attribute__((ext_vector_type(8))) short short8;   // 8 bf16 for MFMA frags
typedef __attribute__((ext_vector_type(8))) u16 ushort8;
typedef __attribute__((ext_vector_type(4))) float f32x4;

// ---------- constants ----------
#define BB 2048
#define SS 8
#define DNUM 8
#define LL 50
#define EDIM 16
#define FDIM 512
#define HID1 256
#define HID2 128
#define VF 100000
#define KDNN 1216          // 1160 padded to 64-multiple
#define ROWS (BB*LL)       // 102400

// ---------- helpers ----------
__device__ inline u16 f2bf(float x) {            // HW RNE cvt (compiler packs)
    return __builtin_bit_cast(u16, __float2bfloat16(x));
}
__device__ inline float bf2f(u16 b) {
    u32 u = ((u32)b) << 16;
    return __builtin_bit_cast(float, u);
}
__device__ inline void load16_lds(const void* g, void* l) {
    __builtin_amdgcn_global_load_lds(
        (const __attribute__((address_space(1))) u32*)g,
        (__attribute__((address_space(3))) u32*)l, 16, 0, 0);
}
__device__ inline float wave_sum(float v) {
    #pragma unroll
    for (int off = 32; off > 0; off >>= 1) v += __shfl_xor(v, off, 64);
    return v;
}
__device__ inline float wave_max(float v) {
    #pragma unroll
    for (int off = 32; off > 0; off >>= 1) v = fmaxf(v, __shfl_xor(v, off, 64));
    return v;
}
__device__ inline void cvt8(const float4& a, const float4& b, ushort8& o) {
    o[0]=f2bf(a.x); o[1]=f2bf(a.y); o[2]=f2bf(a.z); o[3]=f2bf(a.w);
    o[4]=f2bf(b.x); o[5]=f2bf(b.y); o[6]=f2bf(b.z); o[7]=f2bf(b.w);
}

// ---------- K-2: zero used-row flags (re-zeroed every call: determinism) ----------
__global__ __launch_bounds__(256) void zero_flags(u32* __restrict__ f) {
    int i = blockIdx.x * 256 + threadIdx.x;
    if (i < 25024) f[i] = 0;          // 100096 bytes
}

// ---------- K-1: mark rows referenced by hist_ids / feedid ----------
__global__ __launch_bounds__(256) void mark_used(
    const int* __restrict__ hist, const int* __restrict__ feedid,
    unsigned char* __restrict__ flags)
{
    int i = blockIdx.x * 256 + threadIdx.x;
    if (i < ROWS) flags[hist[i]] = 1;
    if (i < BB) flags[feedid[i]] = 1;
}

// ---------- K0 (fused): dedup'd cvt + weight prep + per-b gather ----------
#define CVT_BLKS 25000
#define PREP_BLKS 2112
__global__ __launch_bounds__(256) void prep_all(
    const float* __restrict__ ft, u16* __restrict__ hb,
    const unsigned char* __restrict__ flags,
    const float* __restrict__ w1, const float* __restrict__ dw1,
    const float* __restrict__ dw2,
    u16* __restrict__ WHP_T, u16* __restrict__ WQ_T,
    u16* __restrict__ W1D_T, u16* __restrict__ W2D_T,
    const int* __restrict__ sparse_ids, const float* __restrict__ dense,
    const int* __restrict__ feedid, const float* __restrict__ emb_tables,
    u16* __restrict__ dnn_in, u16* __restrict__ A_q)
{
    int blk = blockIdx.x, t = threadIdx.x;
    if (blk < CVT_BLKS) {
        int r = blk * 4 + (t >> 6);
        if (flags[r]) {
            const float* src = ft + (size_t)r * FDIM + (t & 63) * 8;
            float4 a = *(const float4*)src;
            float4 b = *(const float4*)(src + 4);
            ushort8 o; cvt8(a, b, o);
            *(ushort8*)(hb + (size_t)r * FDIM + (t & 63) * 8) = o;
        }
    } else if (blk < CVT_BLKS + PREP_BLKS) {
        int idx = (blk - CVT_BLKS) * 256 + t;
        if (idx < 131072) {
            int n = idx >> 10, k = idx & 1023;
            float v;
            if (k < 512) v = w1[(512 + k) * 128 + n] - w1[(1024 + k) * 128 + n];
            else         v = w1[(1024 + k) * 128 + n];   // 1536 + (k-512)
            WHP_T[n * 1024 + k] = f2bf(v);
        } else if (idx < 196608) {
            int i = idx - 131072;
            int n = i >> 9, k = i & 511;
            WQ_T[n * 512 + k] = f2bf(w1[k * 128 + n] + w1[(1024 + k) * 128 + n]);
        } else if (idx < 507904) {
            int i = idx - 196608;
            int n = i / KDNN, k = i - n * KDNN;
            W1D_T[i] = (k < 1160) ? f2bf(dw1[k * HID1 + n]) : (u16)0;
        } else if (idx < 540672) {
            int i = idx - 507904;
            int n = i >> 8, k = i & 255;
            W2D_T[i] = f2bf(dw2[k * HID2 + n]);
        }
    } else {
        int b = blk - (CVT_BLKS + PREP_BLKS);
        u16* drow = dnn_in + (size_t)b * KDNN;
        if (t < 128) {
            int s = t >> 4, e = t & 15;
            int id = sparse_ids[b * SS + s];
            float v = emb_tables[(size_t)s * 1600000 + (size_t)id * EDIM + e];
            drow[t] = f2bf(v);
        } else if (t < 136) {
            drow[t] = f2bf(dense[b * DNUM + (t - 128)]);
        } else if (t < 192) {
            drow[1160 + (t - 136)] = 0;   // K padding
        }
        int fid = feedid[b];
        float2 f = *(const float2*)&ft[(size_t)fid * FDIM + t * 2];
        u16 u0 = f2bf(f.x), u1 = f2bf(f.y);
        drow[136 + t * 2] = u0;
        drow[136 + t * 2 + 1] = u1;
        A_q[(size_t)b * FDIM + t * 2] = u0;
        A_q[(size_t)b * FDIM + t * 2 + 1] = u1;
    }
}

// ---------- K2: generic bf16 MFMA GEMM, templated M-tile ----------
template<int BM, bool RELU, bool OUT_BF16>
__global__ __launch_bounds__(256, 4) void gemm_bt(
    const u16* __restrict__ A, int lda,
    const u16* __restrict__ BT, int ldb,
    const float* __restrict__ bias,
    void* __restrict__ Cv, int M, int N, int K)
{
    constexpr int MI = BM / 32;           // frags per wave in M
    __shared__ u16 As[BM * 64];
    __shared__ u16 Bs[128 * 64];
    int m0 = blockIdx.x * BM, n0 = blockIdx.y * 128;
    int tid = threadIdx.x, wave = tid >> 6, lane = tid & 63;
    int lrow = lane >> 3, lk = (lane & 7) * 8;
    f32x4 acc[MI][4];
    f32x4 zz = {0.f, 0.f, 0.f, 0.f};
    #pragma unroll
    for (int i = 0; i < MI; i++)
        #pragma unroll
        for (int j = 0; j < 4; j++) acc[i][j] = zz;
    int wm = (wave >> 1) * (BM / 2), wn = (wave & 1) * 64;

    for (int kt = 0; kt < K; kt += 64) {
        #pragma unroll
        for (int j = 0; j < MI; ++j) {
            int c = wave * MI + j;
            int row = c * 8 + lrow;
            load16_lds(A + (size_t)(m0 + row) * lda + kt + lk, &As[c * 512]);
        }
        #pragma unroll
        for (int j = 0; j < 4; ++j) {
            int c = wave * 4 + j;
            int row = c * 8 + lrow;
            load16_lds(BT + (size_t)(n0 + row) * ldb + kt + lk, &Bs[c * 512]);
        }
        __syncthreads();
        #pragma unroll
        for (int ks = 0; ks < 2; ++ks) {
            int kk = ks * 32 + (lane >> 4) * 8;
            short8 af[MI], bf[4];
            #pragma unroll
            for (int i = 0; i < MI; i++)
                af[i] = *(const short8*)&As[(wm + i * 16 + (lane & 15)) * 64 + kk];
            #pragma unroll
            for (int j = 0; j < 4; j++)
                bf[j] = *(const short8*)&Bs[(wn + j * 16 + (lane & 15)) * 64 + kk];
            #pragma unroll
            for (int i = 0; i < MI; i++)
                #pragma unroll
                for (int j = 0; j < 4; j++)
                    acc[i][j] = __builtin_amdgcn_mfma_f32_16x16x32_bf16(
                        af[i], bf[j], acc[i][j], 0, 0, 0);
        }
        __syncthreads();
    }
    #pragma unroll
    for (int i = 0; i < MI; i++) {
        #pragma unroll
        for (int j = 0; j < 4; j++) {
            #pragma unroll
            for (int r = 0; r < 4; r++) {
                int row = m0 + wm + i * 16 + (lane >> 4) * 4 + r;
                int col = n0 + wn + j * 16 + (lane & 15);
                float v = acc[i][j][r];
                if (bias) v += bias[col];
                if (RELU) v = fmaxf(v, 0.f);
                size_t off = (size_t)row * N + col;
                if (OUT_BF16) ((u16*)Cv)[off] = f2bf(v);
                else ((float*)Cv)[off] = v;
            }
        }
    }
}

#define MFMA_BF16 __builtin_amdgcn_mfma_f32_16x16x32_bf16

// ---------- K3: DIN GEMM v15 — m97 structure with GATHERED global_load_lds A ----------
// The 12-round lesson: hipcc never keeps register-destined global loads in
// flight (sinks them before use), but global_load_lds needs NO registers so
// arbitrary many fly concurrently under one vmcnt drain (the m97/gemm_bt
// idiom, 874 TF-proven). HB16 is bf16 => the h-gather can go straight
// through global_load_lds with per-lane gathered source addresses (m173).
// Block = 64 rows x 128 cols, 4 waves. Per kt=32 step: 5 gload/wave
// (A-h 1, B-h 2, B-p 2), barrier(drain), compute: 10 ds_read frags +
// q direct (L1-hot, <=3 rows/block) + p=h*q in regs + 16 MFMAs, barrier.
__global__ __launch_bounds__(256, 4) void din_gemm(
    const int* __restrict__ hist_ids, const int* __restrict__ feedid,
    const u16* __restrict__ HB, const u16* __restrict__ WHP_T,
    const float* __restrict__ qw, const float* __restrict__ b1,
    const float* __restrict__ w2v, float* __restrict__ scores)
{
    __shared__ u16 As[64 * 32];       // 4 KB  [row][32k]
    __shared__ u16 BsH[128 * 32];     // 8 KB  [n][32k]
    __shared__ u16 BsP[128 * 32];     // 8 KB
    __shared__ float qbs[3 * 128];
    __shared__ float w2s[128];
    __shared__ float sred[64 * 2];

    int t = threadIdx.x, w = t >> 6, lane = t & 63;
    int m0 = blockIdx.x * 64, b0 = m0 / LL;
    int fr = lane & 15, kg8 = (lane >> 4) * 8;
    int wm = (w >> 1) * 32, wn = (w & 1) * 64;

    // ---- prologue: qw+b1, w2 into LDS ----
    for (int idx = t; idx < 384; idx += 256) {
        int bi = idx >> 7, col = idx & 127;
        int bb = b0 + bi; if (bb > BB - 1) bb = BB - 1;
        qbs[idx] = qw[bb * 128 + col] + b1[col];
    }
    if (t < 128) w2s[t] = w2v[t];

    // ---- per-lane staging source pointers ----
    // A: wave w stages rows w*16..w*16+15; lane covers row w*16+(l>>2),
    //    k-slice (l&3)*8 — gathered per-lane global address.
    const u16* a_src = HB + (size_t)hist_ids[m0 + w * 16 + (lane >> 2)] * FDIM
                          + (lane & 3) * 8;
    // B: wave w stages n-rows w*32..w*32+31 (chunks 2w, 2w+1).
    const u16* b_src0 = WHP_T + (size_t)(w * 32 + (lane >> 2)) * 1024 + (lane & 3) * 8;
    const u16* b_src1 = b_src0 + 16 * 1024;
    // q fragment pointers (compute phase, L1-hot)
    const u16* qp0 = HB + (size_t)feedid[(m0 + wm + fr) / LL] * FDIM + kg8;
    const u16* qp1 = HB + (size_t)feedid[(m0 + wm + 16 + fr) / LL] * FDIM + kg8;

    f32x4 acc[2][4];
    f32x4 zz = {0.f, 0.f, 0.f, 0.f};
    #pragma unroll
    for (int i = 0; i < 2; i++)
        #pragma unroll
        for (int j = 0; j < 4; j++) acc[i][j] = zz;

    for (int kt = 0; kt < 16; ++kt) {
        int ko = kt * 32;
        // ---- stage (5 gload/wave, zero register cost, all in flight) ----
        load16_lds(a_src + ko,        &As[w * 512]);
        load16_lds(b_src0 + ko,       &BsH[(w * 2) * 512]);
        load16_lds(b_src1 + ko,       &BsH[(w * 2 + 1) * 512]);
        load16_lds(b_src0 + 512 + ko, &BsP[(w * 2) * 512]);
        load16_lds(b_src1 + 512 + ko, &BsP[(w * 2 + 1) * 512]);
        __syncthreads();               // vmcnt(0) drain — the only wait

        // ---- compute ----
        ushort8 qv0 = *(const ushort8*)(qp0 + ko);
        ushort8 qv1 = *(const ushort8*)(qp1 + ko);
        short8 ah0 = *(const short8*)&As[(wm + fr) * 32 + kg8];
        short8 ah1 = *(const short8*)&As[(wm + 16 + fr) * 32 + kg8];
        short8 bh[4], bp[4];
        #pragma unroll
        for (int j = 0; j < 4; ++j) {
            int n = wn + j * 16 + fr;
            bh[j] = *(const short8*)&BsH[n * 32 + kg8];
            bp[j] = *(const short8*)&BsP[n * 32 + kg8];
        }
        // h-stream MFMAs (q loads land underneath)
        #pragma unroll
        for (int j = 0; j < 4; ++j) {
            acc[0][j] = MFMA_BF16(ah0, bh[j], acc[0][j], 0, 0, 0);
            acc[1][j] = MFMA_BF16(ah1, bh[j], acc[1][j], 0, 0, 0);
        }
        // p = h*q (bf16), then p-stream MFMAs
        ushort8 hv0 = __builtin_bit_cast(ushort8, ah0);
        ushort8 hv1 = __builtin_bit_cast(ushort8, ah1);
        ushort8 pv0, pv1;
        #pragma unroll
        for (int e = 0; e < 8; ++e) {
            pv0[e] = f2bf(bf2f(hv0[e]) * bf2f(qv0[e]));
            pv1[e] = f2bf(bf2f(hv1[e]) * bf2f(qv1[e]));
        }
        short8 ap0 = __builtin_bit_cast(short8, pv0);
        short8 ap1 = __builtin_bit_cast(short8, pv1);
        #pragma unroll
        for (int j = 0; j < 4; ++j) {
            acc[0][j] = MFMA_BF16(ap0, bp[j], acc[0][j], 0, 0, 0);
            acc[1][j] = MFMA_BF16(ap1, bp[j], acc[1][j], 0, 0, 0);
        }
        __syncthreads();               // before next-step overwrite
    }

    // ---- epilogue: score[row] = sum_col relu(acc + qw + b1) * w2 ----
    #pragma unroll
    for (int i = 0; i < 2; ++i) {
        #pragma unroll
        for (int r = 0; r < 4; ++r) {
            int rl = wm + i * 16 + (lane >> 4) * 4 + r;
            int bi = (m0 + rl) / LL - b0;
            float s = 0.f;
            #pragma unroll
            for (int j = 0; j < 4; ++j) {
                int col = wn + j * 16 + fr;
                float v = acc[i][j][r] + qbs[bi * 128 + col];
                s += fmaxf(v, 0.f) * w2s[col];
            }
            s += __shfl_xor(s, 1, 64);
            s += __shfl_xor(s, 2, 64);
            s += __shfl_xor(s, 4, 64);
            s += __shfl_xor(s, 8, 64);
            if (fr == 0) sred[rl * 2 + (w & 1)] = s;
        }
    }
    __syncthreads();
    if (t < 64) scores[m0 + t] = sred[t * 2] + sred[t * 2 + 1];
}

// ---------- K4: softmax over L + user_interest (bf16 table, L3-hot) ----------
__global__ __launch_bounds__(256) void softmax_ui(
    const float* __restrict__ scores, const int* __restrict__ hist_ids,
    const u16* __restrict__ HB, u16* __restrict__ dnn_in)
{
    int b = blockIdx.x, t = threadIdx.x;
    int wave = t >> 6, lane = t & 63;
    __shared__ float sc[56];
    __shared__ int hid[56];
    if (t >= 64 && t < 64 + LL) hid[t - 64] = hist_ids[b * LL + (t - 64)];
    if (wave == 0) {
        float x = (lane < LL) ? scores[b * LL + lane] : -1e30f;
        float mx = wave_max(x);
        float e = (lane < LL) ? __expf(x - mx) : 0.f;
        float s = wave_sum(e);
        if (lane < LL) sc[lane] = e / s;
    }
    __syncthreads();
    int d = t * 2;
    float a0 = 0.f, a1 = 0.f;
    #pragma unroll 5
    for (int l = 0; l < LL; ++l) {
        u32 v = *(const u32*)(HB + (size_t)hid[l] * FDIM + d);
        float al = sc[l];
        a0 += al * bf2f((u16)(v & 0xffff));
        a1 += al * bf2f((u16)(v >> 16));
    }
    dnn_in[(size_t)b * KDNN + 648 + d] = f2bf(a0);
    dnn_in[(size_t)b * KDNN + 648 + d + 1] = f2bf(a1);
}

// ---------- K5: MMOE + task heads ----------
__global__ __launch_bounds__(256) void mmoe_head(
    const float* __restrict__ dnn_out, const float* __restrict__ expert_w,
    const float* __restrict__ gate_w, const float* __restrict__ out_w,
    const float* __restrict__ out_b, float* __restrict__ out)
{
    int wave = threadIdx.x >> 6, lane = threadIdx.x & 63;
    int b = blockIdx.x * 4 + wave;
    __shared__ float ds[4][128];
    __shared__ float eo[4][64];
    __shared__ float gt[4][32];
    ds[wave][lane] = dnn_out[b * 128 + lane];
    ds[wave][lane + 64] = dnn_out[b * 128 + 64 + lane];
    __syncthreads();
    int e = lane >> 3, o = lane & 7;
    float acc = 0.f;
    for (int k = 0; k < 128; ++k)
        acc += ds[wave][k] * expert_w[(e * 128 + k) * 8 + o];
    eo[wave][lane] = acc;
    if (lane < 32) {
        int tt = lane >> 3, ee = lane & 7;
        float g = 0.f;
        for (int k = 0; k < 128; ++k)
            g += ds[wave][k] * gate_w[(tt * 128 + k) * 8 + ee];
        float m = g;
        #pragma unroll
        for (int off = 4; off; off >>= 1) m = fmaxf(m, __shfl_xor(m, off, 8));
        float ex = __expf(g - m);
        float s = ex;
        #pragma unroll
        for (int off = 4; off; off >>= 1) s += __shfl_xor(s, off, 8);
        gt[wave][lane] = ex / s;
    }
    __syncthreads();
    if (lane < 32) {
        int tt = lane >> 3, o2 = lane & 7;
        float to = 0.f;
        #pragma unroll
        for (int ee = 0; ee < 8; ++ee)
            to += gt[wave][tt * 8 + ee] * eo[wave][ee * 8 + o2];
        float pl = to * out_w[tt * 8 + o2];
        #pragma unroll
        for (int off = 4; off; off >>= 1) pl += __shfl_xor(pl, off, 8);
        if (o2 == 0) {
            float logit = pl + out_b[tt];
            out[b * 4 + tt] = 1.f / (1.f + __expf(-logit));
        }
    }
}

// ---------- host ----------
extern "C" void kernel_launch(void* const* d_in, const int* in_sizes, int n_in,
                              void* d_out, int out_size, void* d_ws, size_t ws_size,
                              hipStream_t stream)
{
    const int*   sparse_ids = (const int*)d_in[0];
    const float* dense      = (const float*)d_in[1];
    const int*   feedid     = (const int*)d_in[2];
    const int*   hist_ids   = (const int*)d_in[3];
    const float* emb_tables = (const float*)d_in[4];
    const float* feed_table = (const float*)d_in[5];
    const float* attn_w1    = (const float*)d_in[6];
    const float* attn_b1    = (const float*)d_in[7];
    const float* attn_w2    = (const float*)d_in[8];
    const float* attn_b2    = (const float*)d_in[9];
    const float* dnn_w1     = (const float*)d_in[10];
    const float* dnn_b1     = (const float*)d_in[11];
    const float* dnn_w2     = (const float*)d_in[12];
    const float* dnn_b2     = (const float*)d_in[13];
    const float* expert_w   = (const float*)d_in[14];
    const float* gate_w     = (const float*)d_in[15];
    const float* out_w      = (const float*)d_in[16];
    const float* out_b      = (const float*)d_in[17];
    float* out = (float*)d_out;

    char* ws = (char*)d_ws;
    size_t off = 0;
    auto alloc = [&](size_t bytes) {
        char* p = ws + off;
        off += (bytes + 255) & ~(size_t)255;
        return p;
    };
    u16* WHP_T = (u16*)alloc(131072 * 2);
    u16* WQ_T  = (u16*)alloc(65536 * 2);
    u16* W1D_T = (u16*)alloc((size_t)HID1 * KDNN * 2);
    u16* W2D_T = (u16*)alloc((size_t)HID2 * HID1 * 2);
    u16* AQ    = (u16*)alloc((size_t)BB * FDIM * 2);
    float* QW  = (float*)alloc((size_t)BB * 128 * 4);
    u16* DNNIN = (u16*)alloc((size_t)BB * KDNN * 2);
    u16* Z     = (u16*)alloc((size_t)BB * HID1 * 2);
    float* DOUT= (float*)alloc((size_t)BB * HID2 * 4);
    float* SCORES = (float*)alloc((size_t)ROWS * 4);
    unsigned char* FLAGS = (unsigned char*)alloc(100096);
    u16* HB16  = (u16*)alloc((size_t)VF * FDIM * 2);   // 102.4 MB

    zero_flags<<<98, 256, 0, stream>>>((u32*)FLAGS);
    mark_used<<<400, 256, 0, stream>>>(hist_ids, feedid, FLAGS);
    prep_all<<<CVT_BLKS + PREP_BLKS + BB, 256, 0, stream>>>(
        feed_table, HB16, FLAGS, attn_w1, dnn_w1, dnn_w2,
        WHP_T, WQ_T, W1D_T, W2D_T,
        sparse_ids, dense, feedid, emb_tables, DNNIN, AQ);
    gemm_bt<32, false, false><<<dim3(BB / 32, 1), 256, 0, stream>>>(
        AQ, 512, WQ_T, 512, nullptr, QW, BB, 128, 512);
    din_gemm<<<ROWS / 64, 256, 0, stream>>>(
        hist_ids, feedid, HB16, WHP_T, QW, attn_b1, attn_w2, SCORES);
    softmax_ui<<<BB, 256, 0, stream>>>(SCORES, hist_ids, HB16, DNNIN);
    gemm_bt<32, true, true><<<dim3(BB / 32, HID1 / 128), 256, 0, stream>>>(
        DNNIN, KDNN, W1D_T, KDNN, dnn_b1, Z, BB, HID1, KDNN);
    gemm_bt<32, true, false><<<dim3(BB / 32, 1), 256, 0, stream>>>(
        Z, HID1, W2D_T, HID1, dnn_b2, DOUT, BB, HID2, HID1);
    mmoe_head<<<BB / 4, 256, 0, stream>>>(DOUT, expert_w, gate_w, out_w,
                                          out_b, out);
}